// Round 13
// baseline (692.985 us; speedup 1.0000x reference)
//
#include <hip/hip_runtime.h>
#include <hip/hip_fp16.h>
#include <math.h>

#define CC 32
#define CHUNK 4096   // 256 threads * 16 elems, for the rptr scan
#define NCPY 16      // atomic privatization copies
#define REDB 1024    // block size for reduce/permfill (must match between them)

static inline int cdiv(long long a, int b) { return (int)((a + b - 1) / b); }

// unpack 4 halves (int2) -> float4
__device__ inline float4 h4f(int2 r) {
  __half2 lo = *reinterpret_cast<__half2*>(&r.x);
  __half2 hi = *reinterpret_cast<__half2*>(&r.y);
  float2 a = __half22float2(lo), b = __half22float2(hi);
  return make_float4(a.x, a.y, b.x, b.y);
}

// ---------- packed privatized degree count ----------
__global__ void k_cnt(const int* __restrict__ src, const int* __restrict__ dst,
                      int* __restrict__ priv, int E, int N) {
  int e = blockIdx.x * blockDim.x + threadIdx.x;
  if (e >= E) return;
  int* p = priv + (size_t)(blockIdx.x & (NCPY - 1)) * N;
  atomicAdd(&p[src[e]], 1 << 16);
  atomicAdd(&p[dst[e]], 1);
}

// per node: sum copies -> deg (->dis), cnt; rewrite priv to per-copy exclusive
// cursor bases; per-block degree histogram -> histmat[block][64]
__global__ void k_reduce(int* __restrict__ priv, float* __restrict__ dis,
                         int* __restrict__ cnt, int* __restrict__ histmat, int N) {
  __shared__ int lh[64];
  if (threadIdx.x < 64) lh[threadIdx.x] = 0;
  __syncthreads();
  int n = blockIdx.x * REDB + threadIdx.x;
  if (n < N) {
    int vals[NCPY];
    int tot = 0;
#pragma unroll
    for (int c = 0; c < NCPY; ++c) {
      vals[c] = priv[(size_t)c * N + n];
      tot += vals[c];
    }
    int deg = tot >> 16, cv = tot & 0xFFFF;
    dis[n] = (deg > 0) ? rsqrtf((float)deg) : 0.f;
    cnt[n] = cv;
    int acc = 0;
#pragma unroll
    for (int c = 0; c < NCPY; ++c) {
      priv[(size_t)c * N + n] = acc;
      acc += vals[c] & 0xFFFF;
    }
    atomicAdd(&lh[min(cv, 63)], 1);
  }
  __syncthreads();
  if (threadIdx.x < 64) histmat[blockIdx.x * 64 + threadIdx.x] = lh[threadIdx.x];
}

// column scan: histmat[b][bin] -> absolute base of (block b, bin) in perm
__global__ void k_scanhist2(int* __restrict__ histmat, int nb) {
  int lane = threadIdx.x;  // 0..63
  int tot = 0;
  for (int i = 0; i < nb; ++i) tot += histmat[i * 64 + lane];
  __shared__ int sh[64], pf[64];
  sh[lane] = tot;
  __syncthreads();
  if (lane == 0) {
    int acc = 0;
    for (int b = 0; b < 64; ++b) { pf[b] = acc; acc += sh[b]; }
  }
  __syncthreads();
  int acc = pf[lane];
  for (int i = 0; i < nb; ++i) {
    int v = histmat[i * 64 + lane];
    histmat[i * 64 + lane] = acc;
    acc += v;
  }
}

// no global atomics: LDS rank + precomputed per-(block,bin) base
__global__ void k_permfill2(const int* __restrict__ cnt, const int* __restrict__ histmat,
                            int* __restrict__ perm, int N) {
  __shared__ int lh[64], lbase[64];
  if (threadIdx.x < 64) lh[threadIdx.x] = 0;
  __syncthreads();
  int i = blockIdx.x * REDB + threadIdx.x;
  int bin = 0, rank = 0;
  bool act = (i < N);
  if (act) {
    bin = min(cnt[i], 63);
    rank = atomicAdd(&lh[bin], 1);
  }
  __syncthreads();
  if (threadIdx.x < 64) lbase[threadIdx.x] = histmat[blockIdx.x * 64 + threadIdx.x];
  __syncthreads();
  if (act) perm[lbase[bin] + rank] = i;
}

// ---------- CSR rptr: chunk sums -> serial chunk scan -> per-chunk fill ----------
__global__ void k_chunksum(const int* __restrict__ cnt, int* __restrict__ csum, int N) {
  int base = blockIdx.x * CHUNK;
  int v = 0;
  for (int i = threadIdx.x; i < CHUNK; i += 256) {
    int idx = base + i;
    if (idx < N) v += cnt[idx];
  }
  for (int m = 32; m; m >>= 1) v += __shfl_xor(v, m);
  __shared__ int ws[4];
  if ((threadIdx.x & 63) == 0) ws[threadIdx.x >> 6] = v;
  __syncthreads();
  if (threadIdx.x == 0) csum[blockIdx.x] = ws[0] + ws[1] + ws[2] + ws[3];
}

__global__ void k_scancsum(int* __restrict__ csum, int nb, int* __restrict__ rptr,
                           int N, int tot) {
  int acc = 0;
  for (int i = 0; i < nb; ++i) { int v = csum[i]; csum[i] = acc; acc += v; }
  rptr[N] = tot;
}

__global__ void k_fillrptr(int* __restrict__ cnt, const int* __restrict__ csum,
                           int* __restrict__ rptr, int N) {
  int base = blockIdx.x * CHUNK + threadIdx.x * 16;
  int v[16];
  int tot = 0;
#pragma unroll
  for (int q = 0; q < 16; ++q) {
    int idx = base + q;
    v[q] = (idx < N) ? cnt[idx] : 0;
    tot += v[q];
  }
  __shared__ int sh[256];
  sh[threadIdx.x] = tot;
  __syncthreads();
  for (int off = 1; off < 256; off <<= 1) {
    int add = (threadIdx.x >= off) ? sh[threadIdx.x - off] : 0;
    __syncthreads();
    sh[threadIdx.x] += add;
    __syncthreads();
  }
  int excl = sh[threadIdx.x] - tot + csum[blockIdx.x];
#pragma unroll
  for (int q = 0; q < 16; ++q) {
    int idx = base + q;
    if (idx < N) rptr[idx] = excl;
    excl += v[q];
  }
}

// fill interleaved edge records eg[slot] = {src, bits(-dis*dis)}
__global__ void k_fill3(const int* __restrict__ src, const int* __restrict__ dst,
                        const float* __restrict__ dis, const int* __restrict__ rptr,
                        int* __restrict__ priv, int2* __restrict__ eg, int E, int N) {
  int e = blockIdx.x * blockDim.x + threadIdx.x;
  if (e >= E) return;
  int s = src[e], d = dst[e];
  int* pc = priv + (size_t)(blockIdx.x & (NCPY - 1)) * N;
  int p = rptr[d] + atomicAdd(&pc[d], 1);
  int2 v;
  v.x = s;
  v.y = __float_as_int(-dis[s] * dis[d]);
  eg[p] = v;
}

// ---------- fused Cheb step: f32 gather-prop + recurrence + out += Tx@W ----
// one 8-lane group per node (lane = 4 channels); LPT perm (heaviest first).
// Fast path: 16-edge strips, all 16 row loads issued before consumption.
__global__ void k_cheb4(const float4* __restrict__ x_in4,
                        const float4* __restrict__ x_sub4,
                        const int* __restrict__ rptr, const int2* __restrict__ eg,
                        const float* __restrict__ W, const int* __restrict__ perm,
                        float scale, float4* __restrict__ tx_out4,
                        float4* __restrict__ out4, int N) {
  __shared__ float wl[1024];
  for (int i = threadIdx.x; i < 1024; i += 256) wl[i] = W[i];
  __syncthreads();
  int gid = blockIdx.x * 32 + (threadIdx.x >> 3);
  int lane = threadIdx.x & 7;
  if (gid >= N) return;
  int node = perm[N - 1 - gid];
  int beg = rptr[node], end = rptr[node + 1];
  float tx = 0.f, ty = 0.f, tz = 0.f, tw = 0.f;
  int base = beg;
  // fast path: full 16-edge strips (no masking; 16 loads in flight)
  for (; base + 16 <= end; base += 16) {
    int2 vA = eg[base + lane];
    int2 vB = eg[base + 8 + lane];
    int sjA = vA.x, sjB = vB.x;
    float wjA = __int_as_float(vA.y), wjB = __int_as_float(vB.y);
    float4 j[16];
#pragma unroll
    for (int q = 0; q < 8; ++q) {
      int sA = __shfl(sjA, q, 8);
      j[q] = x_in4[(long long)sA * 8 + lane];
    }
#pragma unroll
    for (int q = 0; q < 8; ++q) {
      int sB = __shfl(sjB, q, 8);
      j[q + 8] = x_in4[(long long)sB * 8 + lane];
    }
#pragma unroll
    for (int q = 0; q < 8; ++q) {
      float w = __shfl(wjA, q, 8);
      tx += w * j[q].x; ty += w * j[q].y; tz += w * j[q].z; tw += w * j[q].w;
    }
#pragma unroll
    for (int q = 0; q < 8; ++q) {
      float w = __shfl(wjB, q, 8);
      tx += w * j[q + 8].x; ty += w * j[q + 8].y;
      tz += w * j[q + 8].z; tw += w * j[q + 8].w;
    }
  }
  // tail: masked 8-wide path
  for (; base < end; base += 8) {
    int rem = end - base;
    int sj = 0; float wjv = 0.f;
    if (lane < rem) {
      int2 v = eg[base + lane];
      sj = v.x;
      wjv = __int_as_float(v.y);
    }
    int cnt = rem < 8 ? rem : 8;
    for (int q = 0; q < cnt; ++q) {
      int s = __shfl(sj, q, 8);
      float w = __shfl(wjv, q, 8);
      float4 j4 = x_in4[(long long)s * 8 + lane];
      tx += w * j4.x; ty += w * j4.y; tz += w * j4.z; tw += w * j4.w;
    }
  }
  long long o = (long long)node * 8 + lane;
  float ta[4] = {scale * tx, scale * ty, scale * tz, scale * tw};
  if (x_sub4) {
    float4 s4 = x_sub4[o];
    ta[0] -= s4.x; ta[1] -= s4.y; ta[2] -= s4.z; ta[3] -= s4.w;
  }
  if (tx_out4) {
    float4 t4 = {ta[0], ta[1], ta[2], ta[3]};
    tx_out4[o] = t4;
  }
  float4 a4 = out4[o];  // issue early; accumulate below
  float ax = 0.f, ay = 0.f, az = 0.f, aw = 0.f;
#pragma unroll
  for (int c = 0; c < 32; ++c) {
    float bc = __shfl(ta[c & 3], c >> 2, 8);
    const float4 w4 = *(const float4*)&wl[c * 32 + lane * 4];
    ax += bc * w4.x; ay += bc * w4.y; az += bc * w4.z; aw += bc * w4.w;
  }
  a4.x += ax; a4.y += ay; a4.z += az; a4.w += aw;
  out4[o] = a4;
}

// out[row][col] = T[row][:] @ W[32][32] + bias[col]   (k=0 term, init)
__global__ void k_gemm32b(const float* __restrict__ T, const float* __restrict__ W,
                          const float* __restrict__ bias, float* __restrict__ out,
                          int N) {
  __shared__ float w[1024];
  for (int i = threadIdx.x; i < 1024; i += 256) w[i] = W[i];
  __syncthreads();
  int row = blockIdx.x * 8 + (threadIdx.x >> 5);
  int col = threadIdx.x & 31;
  if (row >= N) return;
  const float* tr = T + (long long)row * 32;
  float acc = 0.f;
#pragma unroll
  for (int c = 0; c < 32; ++c) acc += tr[c] * w[c * 32 + col];
  out[(long long)row * 32 + col] = acc + bias[col];
}

// h = x @ lin_w stored head-packed HALF: lane l in [0,16) of a row holds
// halves {h0[l], h0[l+16], h1[l], h1[l+16]} (8B/lane, 128B/row).
__global__ void k_gemmh(const float* __restrict__ T, const float* __restrict__ W,
                        __half* __restrict__ h, int N) {
  __shared__ float w[2048];
  for (int i = threadIdx.x; i < 2048; i += 256) w[i] = W[i];
  __syncthreads();
  int row = blockIdx.x * 4 + (threadIdx.x >> 6);
  int col = threadIdx.x & 63;
  if (row >= N) return;
  const float* tr = T + (long long)row * 32;
  float acc = 0.f;
#pragma unroll
  for (int c = 0; c < 32; ++c) acc += tr[c] * w[c * 64 + col];
  int ch = col & 31, hd = col >> 5;
  h[(long long)row * 64 + (ch & 15) * 4 + (ch >> 4) + 2 * hd] = __float2half(acc);
}

// ---------- fused SuperGAT: 16-lane groups, fp16 head-packed h; PACKED half2
// butterfly (one shfl chain carries both heads: 8 DS-ops/edge, no select, no
// broadcast); in-register bl/br; no-max softmax; 16-deep row prefetch; LPT.
__device__ inline void gat_edge(const float4& j4, const float4& i4, const float4& al,
                                float br0, float br1,
                                float& s0, float& s1, float4& v) {
  float d0 = j4.x * i4.x + j4.y * i4.y;
  float d1 = j4.z * i4.z + j4.w * i4.w;
  float b0 = j4.x * al.x + j4.y * al.y;
  float b1 = j4.z * al.z + j4.w * al.w;
  __half2 pd = __floats2half2_rn(d0, d1);
  __half2 pb = __floats2half2_rn(b0, b1);
  unsigned ud = *reinterpret_cast<unsigned*>(&pd);
  unsigned ub = *reinterpret_cast<unsigned*>(&pb);
#pragma unroll
  for (int m = 8; m; m >>= 1) {
    unsigned od = (unsigned)__shfl_xor((int)ud, m, 16);
    unsigned ob = (unsigned)__shfl_xor((int)ub, m, 16);
    __half2 rd = __hadd2(*reinterpret_cast<__half2*>(&ud),
                         *reinterpret_cast<__half2*>(&od));
    __half2 rb = __hadd2(*reinterpret_cast<__half2*>(&ub),
                         *reinterpret_cast<__half2*>(&ob));
    ud = *reinterpret_cast<unsigned*>(&rd);
    ub = *reinterpret_cast<unsigned*>(&rb);
  }
  float2 dd = __half22float2(*reinterpret_cast<__half2*>(&ud));
  float2 bb = __half22float2(*reinterpret_cast<__half2*>(&ub));
  float a0 = (bb.x + br0) / (1.f + __expf(-dd.x));
  float a1 = (bb.y + br1) / (1.f + __expf(-dd.y));
  a0 = (a0 > 0.f) ? a0 : 0.2f * a0;
  a1 = (a1 > 0.f) ? a1 : 0.2f * a1;
  float e0 = __expf(a0), e1 = __expf(a1);
  s0 += e0; s1 += e1;
  v.x += e0 * j4.x; v.y += e0 * j4.y; v.z += e1 * j4.z; v.w += e1 * j4.w;
}

__global__ void k_expgat4(const int2* __restrict__ h2, const int* __restrict__ rptr,
                          const int2* __restrict__ eg, const float* __restrict__ attl,
                          const float* __restrict__ attr, const float* __restrict__ gb,
                          const int* __restrict__ perm, float* __restrict__ y,
                          float* __restrict__ bns, int N) {
  __shared__ float ls[64];
  for (int i = threadIdx.x; i < 64; i += 256) ls[i] = 0.f;
  __syncthreads();
  int gid = blockIdx.x * 16 + (threadIdx.x >> 4);
  int lane = threadIdx.x & 15;
  // per-lane attention vectors for this lane's 4 channels (head-packed layout)
  float4 al = {attl[lane], attl[lane + 16], attl[32 + lane], attl[48 + lane]};
  float4 ar = {attr[lane], attr[lane + 16], attr[32 + lane], attr[48 + lane]};
  if (gid < N) {
    int node = perm[N - 1 - gid];
    float4 i4 = h4f(h2[(long long)node * 16 + lane]);
    // br per head, in-register, f32 reduce (once per node)
    float r0 = i4.x * ar.x + i4.y * ar.y;
    float r1 = i4.z * ar.z + i4.w * ar.w;
#pragma unroll
    for (int m = 8; m; m >>= 1) {
      r0 += __shfl_xor(r0, m, 16);
      r1 += __shfl_xor(r1, m, 16);
    }
    float br0 = r0, br1 = r1;
    float s0 = 0.f, s1 = 0.f;
    float4 v = {0.f, 0.f, 0.f, 0.f};
    // self-loop (j == i; bl computed in-register inside gat_edge)
    gat_edge(i4, i4, al, br0, br1, s0, s1, v);
    int beg = rptr[node], end = rptr[node + 1];
    for (int base = beg; base < end; base += 16) {
      int rem = end - base;
      int sj = 0;
      if (lane < rem) sj = eg[base + lane].x;
      if (rem >= 16) {
        int2 r[16];
#pragma unroll
        for (int q = 0; q < 16; ++q) {
          int s = __shfl(sj, q, 16);
          r[q] = h2[(long long)s * 16 + lane];
        }
#pragma unroll
        for (int q = 0; q < 16; ++q)
          gat_edge(h4f(r[q]), i4, al, br0, br1, s0, s1, v);
      } else {
        int q = 0;
        for (; q + 2 <= rem; q += 2) {
          int sA = __shfl(sj, q, 16);
          int sB = __shfl(sj, q + 1, 16);
          int2 rA = h2[(long long)sA * 16 + lane];
          int2 rB = h2[(long long)sB * 16 + lane];
          gat_edge(h4f(rA), i4, al, br0, br1, s0, s1, v);
          gat_edge(h4f(rB), i4, al, br0, br1, s0, s1, v);
        }
        if (q < rem) {
          int sA = __shfl(sj, q, 16);
          int2 rA = h2[(long long)sA * 16 + lane];
          gat_edge(h4f(rA), i4, al, br0, br1, s0, s1, v);
        }
      }
    }
    float x2a = 0.5f * (v.x / s0 + v.z / s1) + gb[lane];
    float x2b = 0.5f * (v.y / s0 + v.w / s1) + gb[lane + 16];
    float ya = ((x2a > 0.f) ? x2a : 0.01f * x2a) + x2a;
    float yb = ((x2b > 0.f) ? x2b : 0.01f * x2b) + x2b;
    y[(long long)node * 32 + lane] = ya;
    y[(long long)node * 32 + lane + 16] = yb;
    atomicAdd(&ls[lane], ya);
    atomicAdd(&ls[lane + 16], yb);
    atomicAdd(&ls[32 + lane], ya * ya);
    atomicAdd(&ls[32 + lane + 16], yb * yb);
  }
  __syncthreads();
  if (threadIdx.x < 64) atomicAdd(&bns[threadIdx.x], ls[threadIdx.x]);
}

// in-place safe (y may alias out)
__global__ void k_bnfinal(const float* __restrict__ y, const float* __restrict__ bns,
                          const float* __restrict__ g, const float* __restrict__ b,
                          float* __restrict__ out, int N) {
  int i = blockIdx.x * blockDim.x + threadIdx.x;
  if (i >= N * CC) return;
  int c = i & 31;
  float inv_n = 1.f / (float)N;
  float mu = bns[c] * inv_n;
  float var = bns[32 + c] * inv_n - mu * mu;
  out[i] = (y[i] - mu) * rsqrtf(var + 1e-5f) * g[c] + b[c];
}

extern "C" void kernel_launch(void* const* d_in, const int* in_sizes, int n_in,
                              void* d_out, int out_size, void* d_ws, size_t ws_size,
                              hipStream_t stream) {
  const float* patch = (const float*)d_in[0];
  const int* eidx = (const int*)d_in[1];
  // d_in[2] = edge_attr (unused by reference)
  const float* cheb_w = (const float*)d_in[3];
  const float* cheb_b = (const float*)d_in[4];
  const float* lin_w = (const float*)d_in[5];
  const float* att_l = (const float*)d_in[6];
  const float* att_r = (const float*)d_in[7];
  const float* gat_b = (const float*)d_in[8];
  const float* bn_g = (const float*)d_in[9];
  const float* bn_b = (const float*)d_in[10];
  float* out = (float*)d_out;

  const int N = in_sizes[0] / CC;   // 100000
  const int E = in_sizes[1] / 2;    // 1600000
  const int* src = eidx;
  const int* dst = eidx + E;

  // workspace layout (~47 MB); 16B alignment where float4 is used
  float* R0 = (float*)d_ws;                  // N*32 f32 (Tx ping; h overlays R0)
  float* R1 = R0 + (size_t)N * 32;           // N*32 f32 (Tx pong)
  int2* eg = (int2*)(R1 + (size_t)N * 32);   // E int2 (edge src + cheb weight)
  int* grptr = (int*)(eg + E);               // N+2 ints (CSR row ptr)
  int* cnt = grptr + (N + 2);                // N ints (in-degree)
  int* csum = cnt + N;                       // 64 ints (chunk sums)
  float* dis = (float*)(csum + 64);          // N floats
  float* bns = dis + N;                      // 64 floats [zeroed]
  int* perm = (int*)(bns + 64);              // N ints (degree-sorted nodes)
  int* priv = (int*)(perm + N);              // NCPY*N ints (counts) [zeroed]
  int* histmat = priv + (size_t)NCPY * N;    // nbred*64 ints
  __half* h = (__half*)R0;                   // N*64 halves overlays R0 after cheb

  const int B = 256;
  const long long NC = (long long)N * 32;
  int nbred = cdiv(N, REDB);

  hipMemsetAsync(priv, 0, sizeof(int) * (size_t)NCPY * N, stream);
  hipMemsetAsync(bns, 0, sizeof(float) * 64, stream);

  // privatized packed degree counts (16 copies)
  k_cnt<<<cdiv(E, B), B, 0, stream>>>(src, dst, priv, E, N);
  // reduce: dis + cnt + per-copy cursor bases + per-block degree hist
  k_reduce<<<nbred, REDB, 0, stream>>>(priv, dis, cnt, histmat, N);
  // counting-sort bases, then atomic-free permfill
  k_scanhist2<<<1, 64, 0, stream>>>(histmat, nbred);
  k_permfill2<<<nbred, REDB, 0, stream>>>(cnt, histmat, perm, N);

  // CSR rptr over E real edges
  int nb = cdiv(N, CHUNK);
  k_chunksum<<<nb, B, 0, stream>>>(cnt, csum, N);
  k_scancsum<<<1, 1, 0, stream>>>(csum, nb, grptr, N, E);
  k_fillrptr<<<nb, B, 0, stream>>>(cnt, csum, grptr, N);
  // fill interleaved edge records (privatized cursors; same copy map as k_cnt)
  k_fill3<<<cdiv(E, B), B, 0, stream>>>(src, dst, dis, grptr, priv, eg, E, N);

  // ChebConv into d_out: k=0 dense (+bias), k=1..4 fused gather+recurrence+GEMM
  k_gemm32b<<<cdiv(N, 8), B, 0, stream>>>(patch, cheb_w, cheb_b, out, N);
  k_cheb4<<<cdiv(N, 32), B, 0, stream>>>((const float4*)patch, nullptr, grptr, eg,
                                         cheb_w + 1024, perm, 1.f,
                                         (float4*)R0, (float4*)out, N);
  k_cheb4<<<cdiv(N, 32), B, 0, stream>>>((const float4*)R0, (const float4*)patch,
                                         grptr, eg, cheb_w + 2048, perm, 2.f,
                                         (float4*)R1, (float4*)out, N);
  k_cheb4<<<cdiv(N, 32), B, 0, stream>>>((const float4*)R1, (const float4*)R0,
                                         grptr, eg, cheb_w + 3072, perm, 2.f,
                                         (float4*)R0, (float4*)out, N);
  k_cheb4<<<cdiv(N, 32), B, 0, stream>>>((const float4*)R0, (const float4*)R1,
                                         grptr, eg, cheb_w + 4096, perm, 2.f,
                                         nullptr, (float4*)out, N);

  // SuperGAT: h (fp16 head-packed) = x @ lin_w, then fused no-max-softmax
  // gather (1 random request/edge; packed-half2 butterfly) + epilogue
  k_gemmh<<<cdiv(N, 4), B, 0, stream>>>(out, lin_w, h, N);
  k_expgat4<<<cdiv(N, 16), B, 0, stream>>>((const int2*)h, grptr, eg, att_l, att_r,
                                           gat_b, perm, out, bns, N);
  k_bnfinal<<<cdiv(NC, B), B, 0, stream>>>(out, bns, bn_g, bn_b, out, N);
}